// Round 1
// baseline (352.103 us; speedup 1.0000x reference)
//
#include <hip/hip_runtime.h>
#include <hip/hip_bf16.h>
#include <hip/hip_fp16.h>

// Sizes (fixed by the problem)
#define Bsz 8
#define Nn 1024
#define Ss 64
#define Hh 32

typedef _Float16 half8 __attribute__((ext_vector_type(8)));
typedef _Float16 half4 __attribute__((ext_vector_type(4)));
typedef float f32x4 __attribute__((ext_vector_type(4)));

__device__ __forceinline__ void gload_lds16(const _Float16* g, _Float16* l) {
  __builtin_amdgcn_global_load_lds(
      (const __attribute__((address_space(1))) unsigned int*)g,
      (__attribute__((address_space(3))) unsigned int*)l, 16, 0, 0);
}

// ---------------------------------------------------------------------------
// Kernel 1: A[b][t*64+u][m] = (u<32 ? Wu[u][m] : Wc[u-32][m]) * x[b][m][t]  (fp16)
// Grid: 512 blocks (b*64+t), 256 threads.
__global__ __launch_bounds__(256)
void build_a(const float* __restrict__ x, const float* __restrict__ Wu,
             const float* __restrict__ Wc, _Float16* __restrict__ Ah) {
  const int b = blockIdx.x >> 6;
  const int t = blockIdx.x & 63;
  const int tid = threadIdx.x;
  __shared__ float xs[Nn];
  for (int m = tid; m < Nn; m += 256) xs[m] = x[((size_t)(b * Nn + m)) * Ss + t];
  __syncthreads();
  const int m4 = tid * 4;
  const float4 xv = *(const float4*)(&xs[m4]);
  const size_t rowbase = ((size_t)b * 4096 + (size_t)t * 64);
#pragma unroll 4
  for (int u = 0; u < 64; ++u) {
    const float* W = (u < 32) ? (Wu + (size_t)u * Nn) : (Wc + (size_t)(u - 32) * Nn);
    const float4 w = *(const float4*)(&W[m4]);
    half4 o;
    o[0] = (_Float16)(w.x * xv.x);
    o[1] = (_Float16)(w.y * xv.y);
    o[2] = (_Float16)(w.z * xv.z);
    o[3] = (_Float16)(w.w * xv.w);
    *(half4*)(&Ah[(rowbase + u) * Nn + m4]) = o;
  }
}

// ---------------------------------------------------------------------------
// Kernel 2: gh = (fp16) g.   8*1024*1024 elems, 4/thread.
__global__ __launch_bounds__(256)
void conv_g(const float* __restrict__ g, _Float16* __restrict__ gh) {
  const size_t i = ((size_t)blockIdx.x * 256 + threadIdx.x) * 4;
  const float4 v = *(const float4*)(&g[i]);
  half4 o;
  o[0] = (_Float16)v.x; o[1] = (_Float16)v.y; o[2] = (_Float16)v.z; o[3] = (_Float16)v.w;
  *(half4*)(&gh[i]) = o;
}

// ---------------------------------------------------------------------------
// Kernel 3: per-b NT GEMM: C[b] (4096x1024) = A[b] (4096x1024) @ gh[b]^T.
// Both operands K(m)-contiguous. 128x128 tile, BK=32, 4 waves, fp16 MFMA.
__global__ __launch_bounds__(256)
void gemm16(const _Float16* __restrict__ A, const _Float16* __restrict__ G,
            _Float16* __restrict__ C) {
  __shared__ __align__(16) _Float16 As[128 * 32];
  __shared__ __align__(16) _Float16 Gs[128 * 32];
  const int b = blockIdx.z;
  const int row0 = blockIdx.x * 128;
  const int col0 = blockIdx.y * 128;
  const int tid = threadIdx.x;
  const int lane = tid & 63;
  const int wave = tid >> 6;
  const int wr = (wave >> 1) * 64;  // wave row offset in tile
  const int wc = (wave & 1) * 64;   // wave col offset in tile

  const _Float16* Ab = A + ((size_t)b * 4096 + row0) * 1024;
  const _Float16* Gb = G + ((size_t)b * 1024 + col0) * 1024;

  f32x4 acc[4][4] = {};

  const int srow = lane >> 2;        // 0..15 within 16-row chunk
  const int scol = (lane & 3) * 8;   // halves within row (32 halves/row)

  for (int kk = 0; kk < 32; ++kk) {
    const int k0 = kk * 32;
    // stage A-tile and G-tile: each wave 2+2 global_load_lds (16B/lane)
#pragma unroll
    for (int i = 0; i < 2; ++i) {
      const int chunk = wave * 2 + i;          // 0..7, 16 rows each
      const int r = chunk * 16 + srow;
      gload_lds16(Ab + (size_t)r * 1024 + k0 + scol, As + chunk * 512);
      gload_lds16(Gb + (size_t)r * 1024 + k0 + scol, Gs + chunk * 512);
    }
    __syncthreads();

    half8 af[4], bf[4];
#pragma unroll
    for (int mi = 0; mi < 4; ++mi)
      af[mi] = *(const half8*)(&As[(wr + mi * 16 + (lane & 15)) * 32 + (lane >> 4) * 8]);
#pragma unroll
    for (int ni = 0; ni < 4; ++ni)
      bf[ni] = *(const half8*)(&Gs[(wc + ni * 16 + (lane & 15)) * 32 + (lane >> 4) * 8]);
#pragma unroll
    for (int mi = 0; mi < 4; ++mi)
#pragma unroll
      for (int ni = 0; ni < 4; ++ni)
        acc[mi][ni] = __builtin_amdgcn_mfma_f32_16x16x32_f16(af[mi], bf[ni], acc[mi][ni], 0, 0, 0);
    __syncthreads();
  }

  _Float16* Cb = C + ((size_t)b * 4096 + row0) * 1024 + col0;
#pragma unroll
  for (int mi = 0; mi < 4; ++mi)
#pragma unroll
    for (int ni = 0; ni < 4; ++ni)
#pragma unroll
      for (int j = 0; j < 4; ++j) {
        const int r = wr + mi * 16 + (lane >> 4) * 4 + j;
        const int n = wc + ni * 16 + (lane & 15);
        Cb[(size_t)r * 1024 + n] = (_Float16)acc[mi][ni][j];
      }
}

// ---------------------------------------------------------------------------
// Kernel 4: GRU recurrence over t. Block per (b,u) [256 blocks], 256 threads,
// each thread owns 4 n-columns.
__global__ __launch_bounds__(256)
void recur(const _Float16* __restrict__ C, const float* __restrict__ bu,
           const float* __restrict__ bc, const float* __restrict__ h0,
           float* __restrict__ H) {
  const int b = blockIdx.x >> 5;
  const int u = blockIdx.x & 31;
  const int tid = threadIdx.x;
  const float bias_u = bu[u];
  const float bias_c = bc[u];
  float h[4];
#pragma unroll
  for (int k = 0; k < 4; ++k) h[k] = h0[u * Nn + tid + k * 256];
  const _Float16* Cb = C + (size_t)b * 4096 * 1024;
  for (int t = 0; t < 64; ++t) {
    const _Float16* ru = Cb + (size_t)(t * 64 + u) * 1024;
    const _Float16* rc = Cb + (size_t)(t * 64 + 32 + u) * 1024;
#pragma unroll
    for (int k = 0; k < 4; ++k) {
      const int n = tid + k * 256;
      const float yu = (float)ru[n] + bias_u;
      const float yc = (float)rc[n] + bias_c;
      const float s = 1.f / (1.f + expf(-yu));
      const float c = tanhf(yc);
      h[k] = s * h[k] + (1.f - s) * c;
    }
  }
#pragma unroll
  for (int k = 0; k < 4; ++k)
    H[((size_t)b * 32 + u) * Nn + tid + k * 256] = h[k];
}

// ---------------------------------------------------------------------------
// Kernel 5: prediction head, thread per (b,n).
__global__ __launch_bounds__(256)
void head(const float* __restrict__ H, const float* __restrict__ W1,
          const float* __restrict__ b1, const float* __restrict__ W2,
          const float* __restrict__ b2, const float* __restrict__ Wd,
          const float* __restrict__ bd, float* __restrict__ out) {
  const int b = blockIdx.x >> 2;
  const int n = (blockIdx.x & 3) * 256 + threadIdx.x;
  const float* Hb = H + (size_t)b * 32 * Nn;
  float h[32];
#pragma unroll
  for (int u = 0; u < 32; ++u) h[u] = Hb[u * Nn + n];
  float x1[32];
#pragma unroll 4
  for (int v = 0; v < 32; ++v) {
    float a = b1[v];
#pragma unroll
    for (int u = 0; u < 32; ++u) a += W1[v * 32 + u] * h[u];
    x1[v] = a > 0.f ? a : 0.01f * a;
  }
  float x2[32];
#pragma unroll 4
  for (int v = 0; v < 32; ++v) {
    float a = b2[v];
#pragma unroll
    for (int u = 0; u < 32; ++u) a += W2[v * 64 + u] * x1[u];
#pragma unroll
    for (int u = 0; u < 32; ++u) a += W2[v * 64 + 32 + u] * h[u];
    x2[v] = a > 0.f ? a : 0.01f * a;
  }
  float o = bd[n];
#pragma unroll
  for (int v = 0; v < 32; ++v) o += Wd[n * 64 + v] * x2[v];
#pragma unroll
  for (int v = 0; v < 32; ++v) o += Wd[n * 64 + 32 + v] * h[v];
  out[(size_t)b * Nn + n] = o;
}

// ---------------------------------------------------------------------------
extern "C" void kernel_launch(void* const* d_in, const int* in_sizes, int n_in,
                              void* d_out, int out_size, void* d_ws, size_t ws_size,
                              hipStream_t stream) {
  const float* x  = (const float*)d_in[0];
  // d_in[1] = mask (unused)
  const float* g  = (const float*)d_in[2];
  // d_in[3]/d_in[4] = Wf/bf (mathematically unused)
  const float* Wu = (const float*)d_in[5];
  const float* bu = (const float*)d_in[6];
  const float* Wc = (const float*)d_in[7];
  const float* bc = (const float*)d_in[8];
  const float* h0 = (const float*)d_in[9];
  const float* W1 = (const float*)d_in[10];
  const float* b1 = (const float*)d_in[11];
  const float* W2 = (const float*)d_in[12];
  const float* b2 = (const float*)d_in[13];
  const float* Wd = (const float*)d_in[14];
  const float* bd = (const float*)d_in[15];
  float* out = (float*)d_out;

  char* ws = (char*)d_ws;
  _Float16* Ah = (_Float16*)(ws);                         // 8*4096*1024*2 = 64 MB
  _Float16* gh = (_Float16*)(ws + (size_t)(64u << 20));   // 16 MB
  _Float16* Ch = (_Float16*)(ws + (size_t)(80u << 20));   // 64 MB
  float*    Hx = (float*)  (ws + (size_t)(144u << 20));   // 1 MB

  build_a<<<512, 256, 0, stream>>>(x, Wu, Wc, Ah);
  conv_g<<<8192, 256, 0, stream>>>(g, gh);
  dim3 gg(32, 8, 8);
  gemm16<<<gg, 256, 0, stream>>>(Ah, gh, Ch);
  recur<<<256, 256, 0, stream>>>(Ch, bu, bc, h0, Hx);
  head<<<32, 256, 0, stream>>>(Hx, W1, b1, W2, b2, Wd, bd, out);
}

// Round 2
// 252.189 us; speedup vs baseline: 1.3962x; 1.3962x over previous
//
#include <hip/hip_runtime.h>
#include <hip/hip_bf16.h>
#include <hip/hip_fp16.h>

// Sizes (fixed by the problem)
#define Bsz 8
#define Nn 1024
#define Ss 64
#define Hh 32

typedef _Float16 half8 __attribute__((ext_vector_type(8)));
typedef _Float16 half4 __attribute__((ext_vector_type(4)));
typedef float f32x4 __attribute__((ext_vector_type(4)));

__device__ __forceinline__ void gload_lds16(const _Float16* g, _Float16* l) {
  __builtin_amdgcn_global_load_lds(
      (const __attribute__((address_space(1))) unsigned int*)g,
      (__attribute__((address_space(3))) unsigned int*)l, 16, 0, 0);
}

// ---------------------------------------------------------------------------
// Kernel 1: A[b][u*128 + gate*64 + t][m] = Wg[u][m] * x[b][m][t]  (fp16)
// Row layout groups one u with BOTH gates and ALL t into a 128-row band, so a
// 128-row GEMM tile can run the GRU recurrence in its epilogue.
// Grid: 512 blocks (b*64+t), 256 threads.
__global__ __launch_bounds__(256)
void build_a(const float* __restrict__ x, const float* __restrict__ Wu,
             const float* __restrict__ Wc, _Float16* __restrict__ Ah) {
  const int b = blockIdx.x >> 6;
  const int t = blockIdx.x & 63;
  const int tid = threadIdx.x;
  __shared__ float xs[Nn];
  for (int m = tid; m < Nn; m += 256) xs[m] = x[((size_t)(b * Nn + m)) * Ss + t];
  __syncthreads();
  const int m4 = tid * 4;
  const float4 xv = *(const float4*)(&xs[m4]);
  const size_t bbase = (size_t)b * 4096;
#pragma unroll 4
  for (int i = 0; i < 64; ++i) {
    const int u = i & 31;
    const int gate = i >> 5;
    const float* W = (gate == 0) ? (Wu + (size_t)u * Nn) : (Wc + (size_t)u * Nn);
    const float4 w = *(const float4*)(&W[m4]);
    half4 o;
    o[0] = (_Float16)(w.x * xv.x);
    o[1] = (_Float16)(w.y * xv.y);
    o[2] = (_Float16)(w.z * xv.z);
    o[3] = (_Float16)(w.w * xv.w);
    const size_t row = bbase + (size_t)u * 128 + gate * 64 + t;
    *(half4*)(&Ah[row * Nn + m4]) = o;
  }
}

// ---------------------------------------------------------------------------
// Kernel 2: gh = (fp16) g.   8*1024*1024 elems, 4/thread.
__global__ __launch_bounds__(256)
void conv_g(const float* __restrict__ g, _Float16* __restrict__ gh) {
  const size_t i = ((size_t)blockIdx.x * 256 + threadIdx.x) * 4;
  const float4 v = *(const float4*)(&g[i]);
  half4 o;
  o[0] = (_Float16)v.x; o[1] = (_Float16)v.y; o[2] = (_Float16)v.z; o[3] = (_Float16)v.w;
  *(half4*)(&gh[i]) = o;
}

// ---------------------------------------------------------------------------
// Kernel 3: fused GEMM + GRU recurrence.
// Per b: C[b] (4096x1024) = A[b] @ gh[b]^T, 128x128 tile (= one u, both gates,
// all 64 t), BK=32, 4 waves. Epilogue: acc -> LDS fp16, then 128 threads run
// the 64-step recurrence per n-column and write only the final h.
#define CP 130  // padded LDS row stride for the C-tile
__global__ __launch_bounds__(256)
void gemm_recur(const _Float16* __restrict__ A, const _Float16* __restrict__ G,
                const float* __restrict__ bu, const float* __restrict__ bc,
                const float* __restrict__ h0, float* __restrict__ H) {
  __shared__ __align__(16) char smem[128 * CP * 2];  // 33280 B, unioned
  _Float16* As = (_Float16*)smem;            // [128][32] = 8 KB
  _Float16* Gs = (_Float16*)(smem + 8192);   // [128][32] = 8 KB
  _Float16* Cs = (_Float16*)smem;            // [128][CP] fp16, reused after loop

  const int u = blockIdx.x;          // 0..31 (M-block == one hidden unit)
  const int col0 = blockIdx.y * 128; // n-tile
  const int b = blockIdx.z;
  const int tid = threadIdx.x;
  const int lane = tid & 63;
  const int wave = tid >> 6;
  const int wr = (wave >> 1) * 64;
  const int wc = (wave & 1) * 64;

  const _Float16* Ab = A + ((size_t)b * 4096 + (size_t)u * 128) * 1024;
  const _Float16* Gb = G + ((size_t)b * 1024 + col0) * 1024;

  f32x4 acc[4][4] = {};

  const int srow = lane >> 2;       // 0..15 within 16-row chunk
  const int scol = (lane & 3) * 8;  // 8-half slot within 32-half row

  for (int kk = 0; kk < 32; ++kk) {
    const int k0 = kk * 32;
#pragma unroll
    for (int i = 0; i < 2; ++i) {
      const int chunk = wave * 2 + i;  // 0..7, 16 rows each
      const int r = chunk * 16 + srow;
      gload_lds16(Ab + (size_t)r * 1024 + k0 + scol, As + chunk * 512);
      gload_lds16(Gb + (size_t)r * 1024 + k0 + scol, Gs + chunk * 512);
    }
    __syncthreads();

    half8 af[4], bf[4];
#pragma unroll
    for (int mi = 0; mi < 4; ++mi)
      af[mi] = *(const half8*)(&As[(wr + mi * 16 + (lane & 15)) * 32 + (lane >> 4) * 8]);
#pragma unroll
    for (int ni = 0; ni < 4; ++ni)
      bf[ni] = *(const half8*)(&Gs[(wc + ni * 16 + (lane & 15)) * 32 + (lane >> 4) * 8]);
#pragma unroll
    for (int mi = 0; mi < 4; ++mi)
#pragma unroll
      for (int ni = 0; ni < 4; ++ni)
        acc[mi][ni] = __builtin_amdgcn_mfma_f32_16x16x32_f16(af[mi], bf[ni], acc[mi][ni], 0, 0, 0);
    __syncthreads();
  }

  // --- epilogue: acc -> LDS (fp16), rows 0-63 = Yu[t], rows 64-127 = Yc[t]
#pragma unroll
  for (int mi = 0; mi < 4; ++mi)
#pragma unroll
    for (int ni = 0; ni < 4; ++ni)
#pragma unroll
      for (int j = 0; j < 4; ++j) {
        const int r = wr + mi * 16 + (lane >> 4) * 4 + j;
        const int c = wc + ni * 16 + (lane & 15);
        Cs[r * CP + c] = (_Float16)acc[mi][ni][j];
      }
  __syncthreads();

  // --- GRU recurrence: thread j < 128 owns column n = col0 + j
  if (tid < 128) {
    const int n = col0 + tid;
    const float bias_u = bu[u];
    const float bias_c = bc[u];
    float h = h0[u * Nn + n];
    for (int t = 0; t < 64; ++t) {
      const float yu = (float)Cs[t * CP + tid] + bias_u;
      const float yc = (float)Cs[(64 + t) * CP + tid] + bias_c;
      const float s = 1.f / (1.f + __expf(-yu));
      const float e = __expf(-2.f * fabsf(yc));
      float th = (1.f - e) / (1.f + e);
      th = yc < 0.f ? -th : th;
      h = s * h + (1.f - s) * th;
    }
    H[((size_t)b * Hh + u) * Nn + n] = h;
  }
}

// ---------------------------------------------------------------------------
// Kernel 4: prediction head, thread per (b,n).
__global__ __launch_bounds__(256)
void head(const float* __restrict__ H, const float* __restrict__ W1,
          const float* __restrict__ b1, const float* __restrict__ W2,
          const float* __restrict__ b2, const float* __restrict__ Wd,
          const float* __restrict__ bd, float* __restrict__ out) {
  const int b = blockIdx.x >> 2;
  const int n = (blockIdx.x & 3) * 256 + threadIdx.x;
  const float* Hb = H + (size_t)b * Hh * Nn;
  float h[32];
#pragma unroll
  for (int u = 0; u < 32; ++u) h[u] = Hb[u * Nn + n];
  float x1[32];
#pragma unroll 4
  for (int v = 0; v < 32; ++v) {
    float a = b1[v];
#pragma unroll
    for (int u = 0; u < 32; ++u) a += W1[v * 32 + u] * h[u];
    x1[v] = a > 0.f ? a : 0.01f * a;
  }
  float x2[32];
#pragma unroll 4
  for (int v = 0; v < 32; ++v) {
    float a = b2[v];
#pragma unroll
    for (int u = 0; u < 32; ++u) a += W2[v * 64 + u] * x1[u];
#pragma unroll
    for (int u = 0; u < 32; ++u) a += W2[v * 64 + 32 + u] * h[u];
    x2[v] = a > 0.f ? a : 0.01f * a;
  }
  float o = bd[n];
#pragma unroll
  for (int v = 0; v < 32; ++v) o += Wd[n * 64 + v] * x2[v];
#pragma unroll
  for (int v = 0; v < 32; ++v) o += Wd[n * 64 + 32 + v] * h[v];
  out[(size_t)b * Nn + n] = o;
}

// ---------------------------------------------------------------------------
extern "C" void kernel_launch(void* const* d_in, const int* in_sizes, int n_in,
                              void* d_out, int out_size, void* d_ws, size_t ws_size,
                              hipStream_t stream) {
  const float* x  = (const float*)d_in[0];
  // d_in[1] = mask (unused)
  const float* g  = (const float*)d_in[2];
  // d_in[3]/d_in[4] = Wf/bf (mathematically unused)
  const float* Wu = (const float*)d_in[5];
  const float* bu = (const float*)d_in[6];
  const float* Wc = (const float*)d_in[7];
  const float* bc = (const float*)d_in[8];
  const float* h0 = (const float*)d_in[9];
  const float* W1 = (const float*)d_in[10];
  const float* b1 = (const float*)d_in[11];
  const float* W2 = (const float*)d_in[12];
  const float* b2 = (const float*)d_in[13];
  const float* Wd = (const float*)d_in[14];
  const float* bd = (const float*)d_in[15];
  float* out = (float*)d_out;

  char* ws = (char*)d_ws;
  _Float16* Ah = (_Float16*)(ws);                         // 8*4096*1024*2 = 64 MB
  _Float16* gh = (_Float16*)(ws + (size_t)(64u << 20));   // 16 MB
  float*    Hx = (float*)  (ws + (size_t)(80u << 20));    // 1 MB

  build_a<<<512, 256, 0, stream>>>(x, Wu, Wc, Ah);
  conv_g<<<8192, 256, 0, stream>>>(g, gh);
  dim3 gg(32, 8, 8);
  gemm_recur<<<gg, 256, 0, stream>>>(Ah, gh, bu, bc, h0, Hx);
  head<<<32, 256, 0, stream>>>(Hx, W1, b1, W2, b2, Wd, bd, out);
}

// Round 3
// 234.851 us; speedup vs baseline: 1.4993x; 1.0738x over previous
//
#include <hip/hip_runtime.h>
#include <hip/hip_bf16.h>
#include <hip/hip_fp16.h>

// Sizes (fixed by the problem)
#define Bsz 8
#define Nn 1024
#define Ss 64
#define Hh 32

typedef _Float16 half8 __attribute__((ext_vector_type(8)));
typedef _Float16 half4 __attribute__((ext_vector_type(4)));
typedef float f32x4 __attribute__((ext_vector_type(4)));

__device__ __forceinline__ void gload_lds16(const _Float16* g, _Float16* l) {
  __builtin_amdgcn_global_load_lds(
      (const __attribute__((address_space(1))) unsigned int*)g,
      (__attribute__((address_space(3))) unsigned int*)l, 16, 0, 0);
}

// ---------------------------------------------------------------------------
// Kernel 1 "prep" (merged): blocks [0,64): transpose x -> xT[b][t][m] fp16;
// blocks [64,72): Wu,Wc -> Wh[2][32][1024] fp16; blocks >=72: g -> gh fp16.
__global__ __launch_bounds__(256)
void prep(const float* __restrict__ x, const float* __restrict__ Wu,
          const float* __restrict__ Wc, const float* __restrict__ g,
          _Float16* __restrict__ xT, _Float16* __restrict__ Wh,
          _Float16* __restrict__ gh) {
  const int tid = threadIdx.x;
  if (blockIdx.x < 64) {
    // --- transpose: block (b, mtile): x[b][m0..m0+128][0..64] -> xT[b][t][m0..]
    const int b = blockIdx.x >> 3;
    const int m0 = (blockIdx.x & 7) * 128;
    __shared__ _Float16 tile[128 * 68];  // [m][t], stride 68 halves
    const int m = tid >> 1;
    const int hf = tid & 1;
    const float* src = x + ((size_t)(b * Nn + m0 + m)) * Ss + hf * 32;
#pragma unroll
    for (int i = 0; i < 8; ++i) {
      const float4 v = *(const float4*)(src + i * 4);
      half4 o;
      o[0] = (_Float16)v.x; o[1] = (_Float16)v.y;
      o[2] = (_Float16)v.z; o[3] = (_Float16)v.w;
      *(half4*)(&tile[m * 68 + hf * 32 + i * 4]) = o;
    }
    __syncthreads();
    const int t = tid & 63;
    const int q = tid >> 6;  // 0..3 -> m-chunk of 32
    _Float16* dst = xT + ((size_t)(b * 64 + t)) * Nn + m0 + q * 32;
#pragma unroll
    for (int i = 0; i < 4; ++i) {
      half8 o;
#pragma unroll
      for (int e = 0; e < 8; ++e) o[e] = tile[(q * 32 + i * 8 + e) * 68 + t];
      *(half8*)(dst + i * 8) = o;
    }
  } else if (blockIdx.x < 72) {
    // --- W convert: Wh flat [2*32*1024]: first Wu then Wc
    const int w = blockIdx.x - 64;
    const size_t i0 = ((size_t)(w * 256 + tid)) * 32;
#pragma unroll
    for (int i = 0; i < 8; ++i) {
      const size_t i4 = i0 + i * 4;
      const float* s = (i4 < 32768) ? (Wu + i4) : (Wc + (i4 - 32768));
      const float4 v = *(const float4*)s;
      half4 o;
      o[0] = (_Float16)v.x; o[1] = (_Float16)v.y;
      o[2] = (_Float16)v.z; o[3] = (_Float16)v.w;
      *(half4*)(&Wh[i4]) = o;
    }
  } else {
    // --- g convert
    const size_t i = ((size_t)(blockIdx.x - 72) * 256 + tid) * 4;
    const float4 v = *(const float4*)(&g[i]);
    half4 o;
    o[0] = (_Float16)v.x; o[1] = (_Float16)v.y;
    o[2] = (_Float16)v.z; o[3] = (_Float16)v.w;
    *(half4*)(&gh[i]) = o;
  }
}

// ---------------------------------------------------------------------------
// Kernel 2: fused GEMM + GRU recurrence, A built on the fly.
// C[r][n] = sum_k W[gate][k]*x[k][t]*g[n][k], r = gate*64+t, per (u,b).
// 128x128 tile, BK=32, 4 waves. A-frag = pk_mul(W-slice, xT-slice) in regs.
__global__ __launch_bounds__(256)
void gemm_recur(const _Float16* __restrict__ xT, const _Float16* __restrict__ Wh,
                const _Float16* __restrict__ G, const float* __restrict__ bu,
                const float* __restrict__ bc, const float* __restrict__ h0,
                float* __restrict__ H) {
  __shared__ __align__(16) char smem[32768];
  _Float16* Xs = (_Float16*)smem;            // [64][32] halves = 4 KB
  _Float16* Gs = (_Float16*)(smem + 4096);   // [128][32] = 8 KB
  _Float16* Cs = (_Float16*)smem;            // [128][128] swizzled (epilogue)

  const int u = blockIdx.x;          // 0..31
  const int col0 = blockIdx.y * 128; // n-tile
  const int b = blockIdx.z;
  const int tid = threadIdx.x;
  const int lane = tid & 63;
  const int wave = tid >> 6;
  const int wr = (wave >> 1) * 64;   // 0: gate0 rows, 64: gate1 rows
  const int wc = (wave & 1) * 64;
  const int gate = wave >> 1;

  const _Float16* Xb = xT + (size_t)b * 64 * Nn;                 // [t][m]
  const _Float16* Gb = G + ((size_t)b * Nn + col0) * Nn;         // [n][m]
  const _Float16* Wg = Wh + ((size_t)gate * 32 + u) * Nn;        // [k]

  f32x4 acc[4][4] = {};

  const int srow = lane >> 2;
  const int scol = (lane & 3) * 8;
  const int koff = (lane >> 4) * 8;  // k-slice within BK for this lane

  for (int kk = 0; kk < 32; ++kk) {
    const int k0 = kk * 32;
    // stage xT-slice: one gload per wave (16 t-rows x 32 halves)
    gload_lds16(Xb + (size_t)(wave * 16 + srow) * Nn + k0 + scol,
                Xs + wave * 512);
    // stage G-tile: two gloads per wave
#pragma unroll
    for (int i = 0; i < 2; ++i) {
      const int chunk = wave * 2 + i;
      gload_lds16(Gb + (size_t)(chunk * 16 + srow) * Nn + k0 + scol,
                  Gs + chunk * 512);
    }
    // W slice for this lane's k-positions (L2-hot 16B load)
    const half8 wv = *(const half8*)(Wg + k0 + koff);
    __syncthreads();

    half8 af[4], bf[4];
#pragma unroll
    for (int mi = 0; mi < 4; ++mi) {
      const half8 x8 = *(const half8*)(&Xs[(mi * 16 + (lane & 15)) * 32 + koff]);
      af[mi] = wv * x8;  // v_pk_mul_f16: A[r][k] = W[k]*x[k][t]
    }
#pragma unroll
    for (int ni = 0; ni < 4; ++ni)
      bf[ni] = *(const half8*)(&Gs[(wc + ni * 16 + (lane & 15)) * 32 + koff]);
#pragma unroll
    for (int mi = 0; mi < 4; ++mi)
#pragma unroll
      for (int ni = 0; ni < 4; ++ni)
        acc[mi][ni] = __builtin_amdgcn_mfma_f32_16x16x32_f16(af[mi], bf[ni], acc[mi][ni], 0, 0, 0);
    __syncthreads();
  }

  // --- epilogue: acc -> Cs (fp16, XOR-swizzled cols), rows: 0-63 Yu, 64-127 Yc
#pragma unroll
  for (int mi = 0; mi < 4; ++mi)
#pragma unroll
    for (int ni = 0; ni < 4; ++ni)
#pragma unroll
      for (int j = 0; j < 4; ++j) {
        const int r = wr + mi * 16 + (lane >> 4) * 4 + j;
        const int c = wc + ni * 16 + (lane & 15);
        Cs[r * 128 + (c ^ (((r >> 2) & 3) << 3))] = (_Float16)acc[mi][ni][j];
      }
  __syncthreads();

  // --- GRU recurrence: thread j < 128 owns column n = col0 + j
  if (tid < 128) {
    const int n = col0 + tid;
    const float bias_u = bu[u];
    const float bias_c = bc[u];
    float h = h0[u * Nn + n];
    for (int t = 0; t < 64; ++t) {
      const int cc = tid ^ (((t >> 2) & 3) << 3);
      const float yu = (float)Cs[t * 128 + cc] + bias_u;
      const float yc = (float)Cs[(64 + t) * 128 + cc] + bias_c;
      const float s = 1.f / (1.f + __expf(-yu));
      const float e = __expf(-2.f * fabsf(yc));
      float th = (1.f - e) / (1.f + e);
      th = yc < 0.f ? -th : th;
      h = s * h + (1.f - s) * th;
    }
    H[((size_t)b * Hh + u) * Nn + n] = h;
  }
}

// ---------------------------------------------------------------------------
// Kernel 3: prediction head, thread per (b,n). 64 blocks x 128 threads.
__global__ __launch_bounds__(128)
void head(const float* __restrict__ H, const float* __restrict__ W1,
          const float* __restrict__ b1, const float* __restrict__ W2,
          const float* __restrict__ b2, const float* __restrict__ Wd,
          const float* __restrict__ bd, float* __restrict__ out) {
  const int b = blockIdx.x >> 3;
  const int n = (blockIdx.x & 7) * 128 + threadIdx.x;
  const float* Hb = H + (size_t)b * Hh * Nn;
  float h[32];
#pragma unroll
  for (int u = 0; u < 32; ++u) h[u] = Hb[u * Nn + n];
  float x1[32];
#pragma unroll 4
  for (int v = 0; v < 32; ++v) {
    float a = b1[v];
#pragma unroll
    for (int u = 0; u < 32; ++u) a += W1[v * 32 + u] * h[u];
    x1[v] = a > 0.f ? a : 0.01f * a;
  }
  float x2[32];
#pragma unroll 4
  for (int v = 0; v < 32; ++v) {
    float a = b2[v];
#pragma unroll
    for (int u = 0; u < 32; ++u) a += W2[v * 64 + u] * x1[u];
#pragma unroll
    for (int u = 0; u < 32; ++u) a += W2[v * 64 + 32 + u] * h[u];
    x2[v] = a > 0.f ? a : 0.01f * a;
  }
  float o = bd[n];
#pragma unroll
  for (int v = 0; v < 32; ++v) o += Wd[n * 64 + v] * x2[v];
#pragma unroll
  for (int v = 0; v < 32; ++v) o += Wd[n * 64 + 32 + v] * h[v];
  out[(size_t)b * Nn + n] = o;
}

// ---------------------------------------------------------------------------
extern "C" void kernel_launch(void* const* d_in, const int* in_sizes, int n_in,
                              void* d_out, int out_size, void* d_ws, size_t ws_size,
                              hipStream_t stream) {
  const float* x  = (const float*)d_in[0];
  // d_in[1] = mask (unused)
  const float* g  = (const float*)d_in[2];
  // d_in[3]/d_in[4] = Wf/bf (mathematically unused)
  const float* Wu = (const float*)d_in[5];
  const float* bu = (const float*)d_in[6];
  const float* Wc = (const float*)d_in[7];
  const float* bc = (const float*)d_in[8];
  const float* h0 = (const float*)d_in[9];
  const float* W1 = (const float*)d_in[10];
  const float* b1 = (const float*)d_in[11];
  const float* W2 = (const float*)d_in[12];
  const float* b2 = (const float*)d_in[13];
  const float* Wd = (const float*)d_in[14];
  const float* bd = (const float*)d_in[15];
  float* out = (float*)d_out;

  char* ws = (char*)d_ws;
  _Float16* xT = (_Float16*)(ws);                        // 8*64*1024*2 = 1 MB
  _Float16* Wh = (_Float16*)(ws + (size_t)(1u << 20));   // 128 KB
  _Float16* gh = (_Float16*)(ws + (size_t)(2u << 20));   // 16 MB
  float*    Hx = (float*)  (ws + (size_t)(18u << 20));   // 1 MB

  prep<<<72 + 8192, 256, 0, stream>>>(x, Wu, Wc, g, xT, Wh, gh);
  dim3 gg(32, 8, 8);
  gemm_recur<<<gg, 256, 0, stream>>>(xT, Wh, gh, bu, bc, h0, Hx);
  head<<<64, 128, 0, stream>>>(Hx, W1, b1, W2, b2, Wd, bd, out);
}